// Round 2
// baseline (2101.810 us; speedup 1.0000x reference)
//
#include <hip/hip_runtime.h>
#include <math.h>

typedef unsigned short u16;

#define NN 2
#define CC 128
#define HH 64
#define WW 64
#define NHD 4
#define DH 32
#define KSZ 7
#define NB 49
#define PIX (NN*HH*WW)          // 8192 pixels
#define HID 512
#define C4 32
#define CRED 7
#define CHUNK 2048              // pixel chunk for scores / MLP hidden
#define F1M (1u<<20)            // 1M floats = one full NHWC activation

static __device__ __forceinline__ float u2f(u16 u){ return __uint_as_float(((unsigned)u) << 16); }
static __device__ __forceinline__ u16 f2u(float f){          // f32 -> bf16 RNE
    unsigned b = __float_as_uint(f);
    return (u16)((b + 0x7FFFu + ((b >> 16) & 1u)) >> 16);
}

// ---------------- dtype sniffer: bf16 inputs -> flag 0, f32 inputs -> flag 1 ----------------
__global__ void detect_k(const u16* __restrict__ x, int* __restrict__ flag){
    __shared__ float red[256];
    int t = threadIdx.x;
    float mx = 0.f;
    for(int i = t; i < 4096; i += 256){
        float v = fabsf(u2f(x[i]));
        if(v < 1e30f) mx = fmaxf(mx, v);     // ignore inf/nan patterns, plenty of finite-huge ones
    }
    red[t] = mx; __syncthreads();
    for(int s = 128; s > 0; s >>= 1){
        if(t < s) red[t] = fmaxf(red[t], red[t+s]);
        __syncthreads();
    }
    if(t == 0) *flag = (red[0] > 1e6f) ? 1 : 0;
}

// ---------------- convert any input array to f32 ----------------
__global__ void cvt_k(const void* __restrict__ src, float* __restrict__ dst, int n,
                      const int* __restrict__ flag){
    int i = blockIdx.x*256 + threadIdx.x;
    if(i >= n) return;
    dst[i] = (*flag) ? ((const float*)src)[i] : u2f(((const u16*)src)[i]);
}

// ---------------- NCHW (input dtype) -> NHWC f32 ----------------
__global__ void nchw2nhwc_k(const void* __restrict__ x, float* __restrict__ out,
                            const int* __restrict__ flag){
    int id = blockIdx.x*256 + threadIdx.x;           // NHWC flat
    if(id >= NN*HH*WW*CC) return;
    int c = id % CC; int j = (id/CC) % WW; int i = (id/(CC*WW)) % HH; int n = id/(CC*WW*HH);
    size_t src = ((size_t)(n*CC + c)*HH + i)*WW + j;
    out[id] = (*flag) ? ((const float*)x)[src] : u2f(((const u16*)x)[src]);
}

// ---------------- GroupNorm(1,C) ----------------
__global__ void gn_reduce_k(const float* __restrict__ cur, float* __restrict__ stats){
    __shared__ float s1[1024]; __shared__ float s2[1024];
    int n = blockIdx.x, t = threadIdx.x;
    const float* p = cur + (size_t)n*HH*WW*CC;
    float a = 0.f, b = 0.f;
    for(int i = t; i < HH*WW*CC; i += 1024){ float v = p[i]; a += v; b += v*v; }
    s1[t] = a; s2[t] = b; __syncthreads();
    for(int s = 512; s > 0; s >>= 1){
        if(t < s){ s1[t] += s1[t+s]; s2[t] += s2[t+s]; }
        __syncthreads();
    }
    if(t == 0){
        const float inv = 1.f/(float)(HH*WW*CC);
        float mu = s1[0]*inv;
        float var = fmaxf(s2[0]*inv - mu*mu, 0.f);
        stats[n*2]   = mu;
        stats[n*2+1] = rsqrtf(var + 1e-5f);
    }
}

__global__ void gn_apply_k(const float* __restrict__ cur, const float* __restrict__ stats,
                           const float* __restrict__ g, const float* __restrict__ b,
                           float* __restrict__ out){
    int id = blockIdx.x*256 + threadIdx.x;
    if(id >= NN*HH*WW*CC) return;
    int c = id % CC; int n = id/(CC*WW*HH);
    out[id] = (cur[id] - stats[n*2])*stats[n*2+1]*g[c] + b[c];
}

// ---------------- tiled f32 GEMM: C[M,N] = A[M,K] @ W[N,K]^T + bias (+epilogue) ----------------
enum { EPI_NONE = 0, EPI_RES = 1, EPI_GELU = 2, EPI_RELU = 3 };

template<int EPI, int OBF>   // OBF=1 -> store bf16
__global__ void gemm_k(const float* __restrict__ A, const float* __restrict__ W,
                       const float* __restrict__ bias, const float* __restrict__ R,
                       void* __restrict__ Cv, int M, int N, int K){
    __shared__ float As[16][65];
    __shared__ float Bs[16][65];
    const int bn = blockIdx.x*64, bm = blockIdx.y*64;
    const int t = threadIdx.x;               // 256 threads
    const int tx = t & 15, ty = t >> 4;
    float acc[4][4] = {};
    for(int k0 = 0; k0 < K; k0 += 16){
        #pragma unroll
        for(int r = 0; r < 4; r++){
            int e = r*256 + t;
            int m = e >> 4, kk = e & 15;
            As[kk][m] = A[(size_t)(bm+m)*K + k0 + kk];
            Bs[kk][m] = (bn+m < N) ? W[(size_t)(bn+m)*K + k0 + kk] : 0.f;
        }
        __syncthreads();
        #pragma unroll
        for(int kk = 0; kk < 16; kk++){
            float ra[4], rb[4];
            #pragma unroll
            for(int i2 = 0; i2 < 4; i2++) ra[i2] = As[kk][ty*4+i2];
            #pragma unroll
            for(int j2 = 0; j2 < 4; j2++) rb[j2] = Bs[kk][tx*4+j2];
            #pragma unroll
            for(int i2 = 0; i2 < 4; i2++)
                #pragma unroll
                for(int j2 = 0; j2 < 4; j2++)
                    acc[i2][j2] += ra[i2]*rb[j2];
        }
        __syncthreads();
    }
    #pragma unroll
    for(int i2 = 0; i2 < 4; i2++){
        int m = bm + ty*4 + i2;
        #pragma unroll
        for(int j2 = 0; j2 < 4; j2++){
            int nn = bn + tx*4 + j2;
            if(nn < N){
                float v = acc[i2][j2] + bias[nn];
                if(EPI == EPI_RES)  v += R[(size_t)m*N + nn];
                if(EPI == EPI_GELU) v = 0.5f*v*(1.f + erff(v*0.70710678118f));
                if(EPI == EPI_RELU) v = fmaxf(v, 0.f);
                if(OBF) ((u16*)Cv)[(size_t)m*N + nn] = f2u(v);
                else    ((float*)Cv)[(size_t)m*N + nn] = v;
            }
        }
    }
}

// ---------------- neighborhood attention (qkv stored bf16, chunked over pixels) ----------------
__global__ void att_score_k(const u16* __restrict__ qkv, const float* __restrict__ rpb,
                            float* __restrict__ sc, int p0){
    int id = blockIdx.x*256 + threadIdx.x;           // local: (pl, e, nb)
    if(id >= CHUNK*NHD*NB) return;
    int nb = id % NB; int e = (id/NB) % NHD; int pl = id/(NB*NHD);
    int p = p0 + pl;
    int j = p % WW; int i = (p / WW) % HH; int n = p / (WW*HH);
    int ky = nb / KSZ, kx = nb % KSZ;
    int i0 = min(max(i - (KSZ/2), 0), HH - KSZ);
    int j0 = min(max(j - (KSZ/2), 0), WW - KSZ);
    int ni = i0 + ky, nj = j0 + kx;
    const u16* q = qkv + (size_t)p*(3*CC) + e*DH;
    const u16* k = qkv + (size_t)((n*HH + ni)*WW + nj)*(3*CC) + CC + e*DH;
    float acc = 0.f;
    #pragma unroll
    for(int d = 0; d < DH; d++) acc += u2f(q[d])*u2f(k[d]);
    acc *= 0.17677669529663689f;   // 32^-0.5
    int ri = ni - i + (KSZ-1), rj = nj - j + (KSZ-1);
    acc += rpb[(e*(2*KSZ-1) + ri)*(2*KSZ-1) + rj];
    sc[id] = acc;
}

__global__ void att_softmax_k(float* __restrict__ sc){
    int id = blockIdx.x*256 + threadIdx.x;           // local (pl, e)
    if(id >= CHUNK*NHD) return;
    float* s = sc + (size_t)id*NB;
    float m = s[0];
    for(int i = 1; i < NB; i++) m = fmaxf(m, s[i]);
    float sum = 0.f;
    for(int i = 0; i < NB; i++){ float v = __expf(s[i]-m); s[i] = v; sum += v; }
    float r = 1.f/sum;
    for(int i = 0; i < NB; i++) s[i] *= r;
}

__global__ void att_pv_k(const float* __restrict__ sc, const u16* __restrict__ qkv,
                         float* __restrict__ out, int p0){
    int id = blockIdx.x*256 + threadIdx.x;           // local (pl, e, d)
    if(id >= CHUNK*NHD*DH) return;
    int d = id % DH; int e = (id/DH) % NHD; int pl = id/(DH*NHD);
    int p = p0 + pl;
    int j = p % WW; int i = (p / WW) % HH; int n = p / (WW*HH);
    int i0 = min(max(i - (KSZ/2), 0), HH - KSZ);
    int j0 = min(max(j - (KSZ/2), 0), WW - KSZ);
    const float* a = sc + (size_t)(pl*NHD + e)*NB;
    float acc = 0.f;
    #pragma unroll
    for(int nb = 0; nb < NB; nb++){
        int ni = i0 + nb/KSZ, nj = j0 + nb%KSZ;
        acc += a[nb]*u2f(qkv[(size_t)((n*HH + ni)*WW + nj)*(3*CC) + 2*CC + e*DH + d]);
    }
    out[(size_t)p*CC + e*DH + d] = acc;
}

// ---------------- LayerNorm over C per pixel ----------------
__global__ void ln_k(const float* __restrict__ a, const float* __restrict__ g,
                     const float* __restrict__ b, float* __restrict__ out){
    int wave = threadIdx.x >> 6;               // 4 waves/block
    int lane = threadIdx.x & 63;
    int p = blockIdx.x*4 + wave;
    if(p >= PIX) return;
    const float* row = a + (size_t)p*CC;
    float v1 = row[lane], v2 = row[lane+64];
    float s = v1 + v2, q = v1*v1 + v2*v2;
    #pragma unroll
    for(int off = 32; off > 0; off >>= 1){
        s += __shfl_xor(s, off, 64);
        q += __shfl_xor(q, off, 64);
    }
    float mu = s*(1.f/CC);
    float rstd = rsqrtf(fmaxf(q*(1.f/CC) - mu*mu, 0.f) + 1e-5f);
    float* o = out + (size_t)p*CC;
    o[lane]    = (v1-mu)*rstd*g[lane]    + b[lane];
    o[lane+64] = (v2-mu)*rstd*g[lane+64] + b[lane+64];
}

// ---------------- conv3x3 SAME, NHWC in/out, OIHW f32 weights ----------------
__global__ void conv3x3_k(const float* __restrict__ in, const float* __restrict__ w,
                          const float* __restrict__ b, float* __restrict__ out){
    __shared__ float patch[9*CC];
    int p = blockIdx.x;
    int j = p % WW; int i = (p / WW) % HH; int n = p / (WW*HH);
    int t = threadIdx.x;                       // 128 threads = out channel
    for(int idx = t; idx < 9*CC; idx += 128){
        int c = idx % CC; int kk = idx / CC;
        int y = i + kk/3 - 1, x = j + kk%3 - 1;
        float v = 0.f;
        if(y >= 0 && y < HH && x >= 0 && x < WW)
            v = in[(size_t)((n*HH + y)*WW + x)*CC + c];
        patch[kk*CC + c] = v;
    }
    __syncthreads();
    float acc = b[t];
    const float* wo = w + (size_t)t*CC*9;
    for(int c = 0; c < CC; c++){
        #pragma unroll
        for(int kk = 0; kk < 9; kk++)
            acc += patch[kk*CC + c]*wo[c*9 + kk];
    }
    out[(size_t)p*CC + t] = acc;
}

// ---------------- tail ----------------
__global__ void pool_k(const float* __restrict__ y, float* __restrict__ pool){
    int n = blockIdx.x, c = threadIdx.x;       // 128 threads
    const float* p = y + (size_t)n*HH*WW*CC + c;
    float acc = 0.f;
    for(int q = 0; q < HH*WW; q++) acc += p[(size_t)q*CC];
    pool[n*CC + c] = acc*(1.f/(HH*WW));
}

__global__ void ca_k(const float* __restrict__ pool,
                     const float* __restrict__ w1, const float* __restrict__ b1,
                     const float* __restrict__ w2, const float* __restrict__ b2,
                     float* __restrict__ s){
    __shared__ float pl[CC]; __shared__ float t1[CRED];
    int n = blockIdx.x, t = threadIdx.x;       // 128 threads
    pl[t] = pool[n*CC + t];
    __syncthreads();
    if(t < CRED){
        float a = b1[t];
        for(int c = 0; c < CC; c++) a += pl[c]*w1[t*CC + c];
        t1[t] = fmaxf(a, 0.f);
    }
    __syncthreads();
    float a = b2[t];
    #pragma unroll
    for(int r = 0; r < CRED; r++) a += t1[r]*w2[t*CRED + r];
    s[n*CC + t] = 1.f/(1.f + __expf(-a));
}

__global__ void final_k(const float* __restrict__ y, const float* __restrict__ s,
                        const void* __restrict__ xraw, void* __restrict__ outv,
                        const int* __restrict__ flag){
    int id = blockIdx.x*256 + threadIdx.x;     // NCHW flat
    if(id >= NN*CC*HH*WW) return;
    int j = id % WW; int i = (id/WW) % HH; int c = (id/(WW*HH)) % CC; int n = id/(WW*HH*CC);
    float xr = (*flag) ? ((const float*)xraw)[id] : u2f(((const u16*)xraw)[id]);
    float v = y[(size_t)((n*HH + i)*WW + j)*CC + c]*s[n*CC + c] + xr;
    if(*flag) ((float*)outv)[id] = v;
    else      ((u16*)outv)[id] = f2u(v);
}

// ---------------- host ----------------
extern "C" void kernel_launch(void* const* d_in, const int* in_sizes, int n_in,
                              void* d_out, int out_size, void* d_ws, size_t ws_size,
                              hipStream_t stream){
    float* wsf   = (float*)d_ws;
    int*   flagp = (int*)d_ws;                 // ws[0..4)
    float* stats = wsf + 4;                    // 4 floats
    float* poolb = wsf + 8;                    // 256
    float* sbuf  = wsf + 264;                  // 256
    float* Wbase = wsf + 1024;                 // ~556K floats of f32 weights

    // activation arena (floats): base + {cur, xg, qkv16(bf16 in 1.5F), hbuf, scores}
    float* AB    = wsf + 786432;
    float* cur   = AB;                         // [0,1F)
    float* xg    = AB + 1*F1M;                 // [1F,2F)  gn-out / attn-out / conv-out; lnt alias
    u16*   qkv16 = (u16*)(AB + 2*F1M);         // floats [2F,3.5F)
    float* abuf  = AB + 2*F1M;                 // proj-out (qkv dead by then)
    float* lnt   = AB + 1*F1M;                 // alias xg (dead after proj)
    float* hbuf  = AB + 3*F1M;                 // [3F,4F) per-chunk MLP hidden
    float* scores= AB + 4*F1M;                 // [4F,4F+401408)
    float* y1    = AB + 2*F1M;                 // tail c1-out
    float* ybuf  = AB + 3*F1M;                 // tail c2-out
    // peak ws use: (786432 + 4*1048576 + 401408)*4 B ≈ 20.5 MB

    detect_k<<<1, 256, 0, stream>>>((const u16*)d_in[0], flagp);

    // convert all 23 weight arrays to f32 arena
    float* warr[23]; int off = 0;
    for(int i = 0; i < 23; i++){
        int n = in_sizes[i+1];
        warr[i] = Wbase + off;
        cvt_k<<<(n + 255)/256, 256, 0, stream>>>(d_in[i+1], warr[i], n, flagp);
        off += n;
    }
    const float *gng = warr[0], *gnb = warr[1], *qkvw = warr[2], *qkvb_w = warr[3],
                *projw = warr[4], *projb = warr[5], *rpbw = warr[6], *lng = warr[7],
                *lnb = warr[8], *f1w = warr[9], *f1b = warr[10], *f2w = warr[11],
                *f2b = warr[12], *bcw = warr[13], *bcb = warr[14], *c1w = warr[15],
                *c1b = warr[16], *c2w = warr[17], *c2b = warr[18], *ca1w = warr[19],
                *ca1b = warr[20], *ca2w = warr[21], *ca2b = warr[22];

    const int ELEMS = NN*HH*WW*CC;             // 1,048,576

    nchw2nhwc_k<<<ELEMS/256, 256, 0, stream>>>(d_in[0], cur, flagp);

    for(int l = 0; l < 2; l++){
        gn_reduce_k<<<NN, 1024, 0, stream>>>(cur, stats);
        gn_apply_k<<<ELEMS/256, 256, 0, stream>>>(cur, stats, gng + l*CC, gnb + l*CC, xg);

        // qkv: [PIX,384] bf16 out
        gemm_k<EPI_NONE,1><<<dim3(6, PIX/64), 256, 0, stream>>>(
            xg, qkvw + (size_t)l*3*CC*CC, qkvb_w + l*3*CC, nullptr, qkv16, PIX, 3*CC, CC);

        for(int c = 0; c < PIX/CHUNK; c++){
            int p0 = c*CHUNK;
            att_score_k<<<(CHUNK*NHD*NB)/256 + 1, 256, 0, stream>>>(qkv16, rpbw + l*NHD*(2*KSZ-1)*(2*KSZ-1), scores, p0);
            att_softmax_k<<<(CHUNK*NHD)/256, 256, 0, stream>>>(scores);
            att_pv_k<<<(CHUNK*NHD*DH)/256, 256, 0, stream>>>(scores, qkv16, xg, p0);
        }

        // proj + residual(cur) -> abuf
        gemm_k<EPI_RES,0><<<dim3(2, PIX/64), 256, 0, stream>>>(
            xg, projw + (size_t)l*CC*CC, projb + l*CC, cur, abuf, PIX, CC, CC);

        ln_k<<<PIX/4, 256, 0, stream>>>(abuf, lng + l*CC, lnb + l*CC, lnt);

        for(int c = 0; c < PIX/CHUNK; c++){
            const float* Ain = lnt + (size_t)c*CHUNK*CC;
            gemm_k<EPI_GELU,0><<<dim3(HID/64, CHUNK/64), 256, 0, stream>>>(
                Ain, f1w + (size_t)l*HID*CC, f1b + l*HID, nullptr, hbuf, CHUNK, HID, CC);
            gemm_k<EPI_RES,0><<<dim3(CC/64, CHUNK/64), 256, 0, stream>>>(
                hbuf, f2w + (size_t)l*CC*HID, f2b + l*CC, abuf + (size_t)c*CHUNK*CC,
                cur + (size_t)c*CHUNK*CC, CHUNK, CC, HID);
        }
    }

    conv3x3_k<<<PIX, CC, 0, stream>>>(cur, bcw, bcb, xg);
    gemm_k<EPI_RELU,0><<<dim3(1, PIX/64), 256, 0, stream>>>(xg, c1w, c1b, nullptr, y1, PIX, C4, CC);
    gemm_k<EPI_NONE,0><<<dim3(2, PIX/64), 256, 0, stream>>>(y1, c2w, c2b, nullptr, ybuf, PIX, CC, C4);

    pool_k<<<NN, CC, 0, stream>>>(ybuf, poolb);
    ca_k<<<NN, CC, 0, stream>>>(poolb, ca1w, ca1b, ca2w, ca2b, sbuf);
    final_k<<<ELEMS/256, 256, 0, stream>>>(ybuf, sbuf, d_in[0], d_out, flagp);
}

// Round 3
// 428.106 us; speedup vs baseline: 4.9096x; 4.9096x over previous
//
#include <hip/hip_runtime.h>
#include <math.h>

typedef unsigned short u16;

#define NN 2
#define CC 128
#define HH 64
#define WW 64
#define NHD 4
#define DH 32
#define KSZ 7
#define NB 49
#define PIX (NN*HH*WW)          // 8192
#define HID 512
#define C4 32
#define CRED 7

typedef float f32x4 __attribute__((ext_vector_type(4)));
typedef short bf16x8 __attribute__((ext_vector_type(8)));

static __device__ __forceinline__ float u2f(u16 u){ return __uint_as_float(((unsigned)u) << 16); }
static __device__ __forceinline__ u16 f2u(float f){          // f32 -> bf16 RNE
    unsigned b = __float_as_uint(f);
    return (u16)((b + 0x7FFFu + ((b >> 16) & 1u)) >> 16);
}

// ---------------- dtype sniffer ----------------
__global__ void detect_k(const u16* __restrict__ x, int* __restrict__ flag){
    __shared__ float red[256];
    int t = threadIdx.x;
    float mx = 0.f;
    for(int i = t; i < 4096; i += 256){
        float v = fabsf(u2f(x[i]));
        if(v < 1e30f) mx = fmaxf(mx, v);
    }
    red[t] = mx; __syncthreads();
    for(int s = 128; s > 0; s >>= 1){
        if(t < s) red[t] = fmaxf(red[t], red[t+s]);
        __syncthreads();
    }
    if(t == 0) *flag = (red[0] > 1e6f) ? 1 : 0;
}

// ---------------- one-shot weight convert to bf16 arena ----------------
struct PtrTab { const void* p[23]; int off[24]; };

__global__ void cvt_all_k(PtrTab tab, u16* __restrict__ dst, const int* __restrict__ flag, int total){
    int i = blockIdx.x*256 + threadIdx.x;
    if(i >= total) return;
    int a = 0;
    while(i >= tab.off[a+1]) a++;
    int loc = i - tab.off[a];
    dst[i] = (*flag) ? f2u(((const float*)tab.p[a])[loc]) : ((const u16*)tab.p[a])[loc];
}

// conv weights OIHW -> [o][tap][c]
__global__ void repack_conv_k(const u16* __restrict__ src, u16* __restrict__ dst){
    int i = blockIdx.x*256 + threadIdx.x;
    if(i >= CC*CC*9) return;
    int o = i/(9*CC); int rem = i%(9*CC); int tap = rem/CC; int c = rem%CC;
    dst[i] = src[(o*CC + c)*9 + tap];
}

// ---------------- NCHW -> NHWC f32 ----------------
__global__ void nchw2nhwc_k(const void* __restrict__ x, float* __restrict__ out,
                            const int* __restrict__ flag){
    int id = blockIdx.x*256 + threadIdx.x;
    if(id >= NN*HH*WW*CC) return;
    int c = id % CC; int j = (id/CC) % WW; int i = (id/(CC*WW)) % HH; int n = id/(CC*WW*HH);
    size_t src = ((size_t)(n*CC + c)*HH + i)*WW + j;
    out[id] = (*flag) ? ((const float*)x)[src] : u2f(((const u16*)x)[src]);
}

// ---------------- GroupNorm two-stage ----------------
__global__ void gn_r1_k(const float* __restrict__ cur, float* __restrict__ part){
    __shared__ float s1[256]; __shared__ float s2[256];
    int n = blockIdx.x, b = blockIdx.y, t = threadIdx.x;
    const float* p = cur + (size_t)n*(HH*WW*CC) + (size_t)b*8192;
    float a = 0.f, q = 0.f;
    for(int i = t; i < 8192; i += 256){ float v = p[i]; a += v; q += v*v; }
    s1[t] = a; s2[t] = q; __syncthreads();
    for(int s = 128; s > 0; s >>= 1){
        if(t < s){ s1[t] += s1[t+s]; s2[t] += s2[t+s]; }
        __syncthreads();
    }
    if(t == 0){ part[(n*64+b)*2] = s1[0]; part[(n*64+b)*2+1] = s2[0]; }
}

__global__ void gn_r2_k(const float* __restrict__ part, float* __restrict__ stats){
    int n = blockIdx.x, t = threadIdx.x;   // 64 threads
    float a = part[(n*64+t)*2], q = part[(n*64+t)*2+1];
    #pragma unroll
    for(int off = 32; off > 0; off >>= 1){
        a += __shfl_xor(a, off, 64);
        q += __shfl_xor(q, off, 64);
    }
    if(t == 0){
        const float inv = 1.f/(float)(HH*WW*CC);
        float mu = a*inv;
        float var = fmaxf(q*inv - mu*mu, 0.f);
        stats[n*2] = mu; stats[n*2+1] = rsqrtf(var + 1e-5f);
    }
}

__global__ void gn_apply_k(const float* __restrict__ cur, const float* __restrict__ stats,
                           const u16* __restrict__ g, const u16* __restrict__ b,
                           u16* __restrict__ out){
    int id = blockIdx.x*256 + threadIdx.x;
    if(id >= NN*HH*WW*CC) return;
    int c = id % CC; int n = id/(CC*WW*HH);
    out[id] = f2u((cur[id] - stats[n*2])*stats[n*2+1]*u2f(g[c]) + u2f(b[c]));
}

// ---------------- MFMA bf16 GEMM: C[M,N] = A[M,K] @ W[N,K]^T + bias (+epi) ----------------
// block 256 thr = 4 waves, tile 128x128, BK=32. A,W bf16; out f32 / bf16 / both.
enum { EPI_NONE = 0, EPI_RES = 1, EPI_GELU = 2, EPI_RELU = 3 };
enum { OUT_F32 = 0, OUT_BF16 = 1, OUT_BOTH = 2 };
#define LDP 40   // padded row (in bf16) for 32-k tiles

template<int EPI, int OUTM>
__global__ __launch_bounds__(256) void mgemm_k(
    const u16* __restrict__ A, const u16* __restrict__ W, const u16* __restrict__ bias,
    const float* __restrict__ R, float* __restrict__ Cf, u16* __restrict__ Cb,
    int M, int N, int K)
{
    __shared__ __align__(16) u16 As[128*LDP];
    __shared__ __align__(16) u16 Bs[128*LDP];
    const int bm = blockIdx.y*128, bn = blockIdx.x*128;
    const int t = threadIdx.x;
    const int wave = t >> 6, lane = t & 63;
    const int wm = (wave >> 1)*64, wn = (wave & 1)*64;
    const int lg = lane >> 4, lr = lane & 15;
    f32x4 acc[4][4];
    #pragma unroll
    for(int i = 0; i < 4; i++)
        #pragma unroll
        for(int j = 0; j < 4; j++) acc[i][j] = (f32x4){0.f,0.f,0.f,0.f};

    for(int k0 = 0; k0 < K; k0 += 32){
        #pragma unroll
        for(int r = 0; r < 2; r++){
            int e = r*256 + t;            // 0..511
            int row = e >> 2, ks = (e & 3)*8;
            uint4 va = *(const uint4*)(A + (size_t)(bm+row)*K + k0 + ks);
            *(uint4*)&As[row*LDP + ks] = va;
            uint4 vb = (bn+row < N) ? *(const uint4*)(W + (size_t)(bn+row)*K + k0 + ks)
                                    : (uint4){0,0,0,0};
            *(uint4*)&Bs[row*LDP + ks] = vb;
        }
        __syncthreads();
        bf16x8 af[4], bf[4];
        #pragma unroll
        for(int x = 0; x < 4; x++){
            af[x] = *(const bf16x8*)&As[(wm + x*16 + lr)*LDP + lg*8];
            bf[x] = *(const bf16x8*)&Bs[(wn + x*16 + lr)*LDP + lg*8];
        }
        #pragma unroll
        for(int i = 0; i < 4; i++)
            #pragma unroll
            for(int j = 0; j < 4; j++)
                acc[i][j] = __builtin_amdgcn_mfma_f32_16x16x32_bf16(af[i], bf[j], acc[i][j], 0, 0, 0);
        __syncthreads();
    }
    #pragma unroll
    for(int it = 0; it < 4; it++){
        #pragma unroll
        for(int jt = 0; jt < 4; jt++){
            int col = bn + wn + jt*16 + lr;
            if(col >= N) continue;
            #pragma unroll
            for(int reg = 0; reg < 4; reg++){
                int row = bm + wm + it*16 + lg*4 + reg;
                float v = acc[it][jt][reg] + u2f(bias[col]);
                if(EPI == EPI_RES)  v += R[(size_t)row*N + col];
                if(EPI == EPI_GELU) v = 0.5f*v*(1.f + erff(v*0.70710678118f));
                if(EPI == EPI_RELU) v = fmaxf(v, 0.f);
                if(OUTM == OUT_F32 || OUTM == OUT_BOTH) Cf[(size_t)row*N + col] = v;
                if(OUTM == OUT_BF16 || OUTM == OUT_BOTH) Cb[(size_t)row*N + col] = f2u(v);
            }
        }
    }
}

// ---------------- conv3x3 as implicit MFMA GEMM (K = 9*128) ----------------
__global__ __launch_bounds__(256) void mconv_k(
    const u16* __restrict__ in,        // NHWC bf16
    const u16* __restrict__ Wt,        // [o][tap][c] bf16, K=1152
    const u16* __restrict__ bias, u16* __restrict__ Cb)
{
    __shared__ __align__(16) u16 As[128*LDP];
    __shared__ __align__(16) u16 Bs[128*LDP];
    const int bm = blockIdx.y*128, bn = 0;
    const int t = threadIdx.x;
    const int wave = t >> 6, lane = t & 63;
    const int wm = (wave >> 1)*64, wn = (wave & 1)*64;
    const int lg = lane >> 4, lr = lane & 15;
    f32x4 acc[4][4];
    #pragma unroll
    for(int i = 0; i < 4; i++)
        #pragma unroll
        for(int j = 0; j < 4; j++) acc[i][j] = (f32x4){0.f,0.f,0.f,0.f};

    for(int k0 = 0; k0 < 9*CC; k0 += 32){
        int tap = k0/CC; int dy = tap/3 - 1, dx = tap%3 - 1;
        #pragma unroll
        for(int r = 0; r < 2; r++){
            int e = r*256 + t;
            int row = e >> 2, ks = (e & 3)*8;
            int p = bm + row;
            int n = p >> 12, ii = (p & 4095) >> 6, jj = p & 63;
            int y = ii + dy, x = jj + dx;
            uint4 va = (uint4){0,0,0,0};
            if(y >= 0 && y < HH && x >= 0 && x < WW)
                va = *(const uint4*)(in + (size_t)(((n*HH + y)*WW + x))*CC + (k0 % CC) + ks);
            *(uint4*)&As[row*LDP + ks] = va;
            uint4 vb = *(const uint4*)(Wt + (size_t)(bn+row)*(9*CC) + k0 + ks);
            *(uint4*)&Bs[row*LDP + ks] = vb;
        }
        __syncthreads();
        bf16x8 af[4], bf[4];
        #pragma unroll
        for(int x = 0; x < 4; x++){
            af[x] = *(const bf16x8*)&As[(wm + x*16 + lr)*LDP + lg*8];
            bf[x] = *(const bf16x8*)&Bs[(wn + x*16 + lr)*LDP + lg*8];
        }
        #pragma unroll
        for(int i = 0; i < 4; i++)
            #pragma unroll
            for(int j = 0; j < 4; j++)
                acc[i][j] = __builtin_amdgcn_mfma_f32_16x16x32_bf16(af[i], bf[j], acc[i][j], 0, 0, 0);
        __syncthreads();
    }
    #pragma unroll
    for(int it = 0; it < 4; it++){
        #pragma unroll
        for(int jt = 0; jt < 4; jt++){
            int col = wn + jt*16 + lr;
            #pragma unroll
            for(int reg = 0; reg < 4; reg++){
                int row = bm + wm + it*16 + lg*4 + reg;
                Cb[(size_t)row*CC + col] = f2u(acc[it][jt][reg] + u2f(bias[col]));
            }
        }
    }
}

// ---------------- fused neighborhood attention: one block per pixel ----------------
__global__ __launch_bounds__(256) void att_fused_k(
    const u16* __restrict__ qkv, const u16* __restrict__ rpb, u16* __restrict__ out)
{
    __shared__ float qs[CC];
    __shared__ float sc[NHD][NB];
    int p = blockIdx.x;
    int j = p % WW, i = (p/WW) % HH, n = p/(WW*HH);
    int i0 = min(max(i - KSZ/2, 0), HH - KSZ);
    int j0 = min(max(j - KSZ/2, 0), WW - KSZ);
    int t = threadIdx.x;
    if(t < CC) qs[t] = u2f(qkv[(size_t)p*(3*CC) + t]) * 0.17677669529663689f;
    __syncthreads();
    if(t < NHD*NB){
        int e = t/NB, nb = t%NB;
        int ni = i0 + nb/KSZ, nj = j0 + nb%KSZ;
        const u16* kp = qkv + (size_t)((n*HH + ni)*WW + nj)*(3*CC) + CC + e*DH;
        float acc = 0.f;
        #pragma unroll
        for(int ch = 0; ch < 4; ch++){
            union { uint4 u; u16 h[8]; } blk;
            blk.u = *(const uint4*)(kp + ch*8);
            #pragma unroll
            for(int z = 0; z < 8; z++) acc += u2f(blk.h[z]) * qs[e*DH + ch*8 + z];
        }
        int ri = ni - i + (KSZ-1), rj = nj - j + (KSZ-1);
        acc += u2f(rpb[(e*(2*KSZ-1) + ri)*(2*KSZ-1) + rj]);
        sc[e][nb] = acc;
    }
    __syncthreads();
    if(t < NHD){
        float m = sc[t][0];
        #pragma unroll
        for(int q = 1; q < NB; q++) m = fmaxf(m, sc[t][q]);
        float sum = 0.f;
        for(int q = 0; q < NB; q++){ float v = __expf(sc[t][q]-m); sc[t][q] = v; sum += v; }
        float r = 1.f/sum;
        for(int q = 0; q < NB; q++) sc[t][q] *= r;
    }
    __syncthreads();
    if(t < CC){
        int e = t >> 5, d = t & 31;
        float acc = 0.f;
        #pragma unroll
        for(int nb = 0; nb < NB; nb++){
            int ni = i0 + nb/KSZ, nj = j0 + nb%KSZ;
            acc += sc[e][nb]*u2f(qkv[(size_t)((n*HH + ni)*WW + nj)*(3*CC) + 2*CC + e*DH + d]);
        }
        out[(size_t)p*CC + t] = f2u(acc);
    }
}

// ---------------- LayerNorm over C per pixel ----------------
__global__ void ln_k(const float* __restrict__ a, const u16* __restrict__ g,
                     const u16* __restrict__ b, u16* __restrict__ out){
    int wave = threadIdx.x >> 6;
    int lane = threadIdx.x & 63;
    int p = blockIdx.x*4 + wave;
    if(p >= PIX) return;
    const float* row = a + (size_t)p*CC;
    float v1 = row[lane], v2 = row[lane+64];
    float s = v1 + v2, q = v1*v1 + v2*v2;
    #pragma unroll
    for(int off = 32; off > 0; off >>= 1){
        s += __shfl_xor(s, off, 64);
        q += __shfl_xor(q, off, 64);
    }
    float mu = s*(1.f/CC);
    float rstd = rsqrtf(fmaxf(q*(1.f/CC) - mu*mu, 0.f) + 1e-5f);
    u16* o = out + (size_t)p*CC;
    o[lane]    = f2u((v1-mu)*rstd*u2f(g[lane])    + u2f(b[lane]));
    o[lane+64] = f2u((v2-mu)*rstd*u2f(g[lane+64]) + u2f(b[lane+64]));
}

// ---------------- tail: two-stage pool, CA MLP, final ----------------
__global__ void pool1_k(const float* __restrict__ y, float* __restrict__ part){
    int n = blockIdx.x, b = blockIdx.y, c = threadIdx.x;   // 128 threads
    float acc = 0.f;
    for(int i = 0; i < 128; i++)
        acc += y[(size_t)((n*HH*WW) + b*128 + i)*CC + c];
    part[(n*32 + b)*CC + c] = acc;
}

__global__ void pool2_k(const float* __restrict__ part, float* __restrict__ pool){
    int n = blockIdx.x, c = threadIdx.x;
    float acc = 0.f;
    for(int b = 0; b < 32; b++) acc += part[(n*32 + b)*CC + c];
    pool[n*CC + c] = acc*(1.f/(HH*WW));
}

__global__ void ca_k(const float* __restrict__ pool,
                     const u16* __restrict__ w1, const u16* __restrict__ b1,
                     const u16* __restrict__ w2, const u16* __restrict__ b2,
                     float* __restrict__ s){
    __shared__ float pl[CC]; __shared__ float t1[CRED];
    int n = blockIdx.x, t = threadIdx.x;   // 128 threads
    pl[t] = pool[n*CC + t];
    __syncthreads();
    if(t < CRED){
        float a = u2f(b1[t]);
        for(int c = 0; c < CC; c++) a += pl[c]*u2f(w1[t*CC + c]);
        t1[t] = fmaxf(a, 0.f);
    }
    __syncthreads();
    float a = u2f(b2[t]);
    #pragma unroll
    for(int r = 0; r < CRED; r++) a += t1[r]*u2f(w2[t*CRED + r]);
    s[n*CC + t] = 1.f/(1.f + __expf(-a));
}

__global__ void final_k(const float* __restrict__ y, const float* __restrict__ s,
                        const void* __restrict__ xraw, void* __restrict__ outv,
                        const int* __restrict__ flag){
    int id = blockIdx.x*256 + threadIdx.x;     // NCHW flat
    if(id >= NN*CC*HH*WW) return;
    int j = id % WW; int i = (id/WW) % HH; int c = (id/(WW*HH)) % CC; int n = id/(WW*HH*CC);
    float xr = (*flag) ? ((const float*)xraw)[id] : u2f(((const u16*)xraw)[id]);
    float v = y[(size_t)((n*HH + i)*WW + j)*CC + c]*s[n*CC + c] + xr;
    if(*flag) ((float*)outv)[id] = v;
    else      ((u16*)outv)[id] = f2u(v);
}

// ---------------- host ----------------
extern "C" void kernel_launch(void* const* d_in, const int* in_sizes, int n_in,
                              void* d_out, int out_size, void* d_ws, size_t ws_size,
                              hipStream_t stream){
    float* wsf   = (float*)d_ws;
    int*   flagp = (int*)d_ws;
    float* stats = wsf + 4;
    float* gnpart= wsf + 8;                    // 256
    float* popart= wsf + 264;                  // 8192
    float* poolb = wsf + 8456;                 // 256
    float* sbuf  = wsf + 8712;                 // 256

    u16* Wb = (u16*)(wsf + 16384);             // bf16 weight arena
    // per-array offsets (elements)
    static const int wsizes[23] = {256,256,98304,768,32768,256,1352,256,256,131072,1024,
                                   131072,256,147456,128,4096,32,4096,128,896,7,896,128};
    int woff[24]; woff[0] = 0;
    for(int i = 0; i < 23; i++) woff[i+1] = woff[i] + wsizes[i];
    const int WTOT = woff[23];                 // 555759
    u16* Wt = Wb + 555760;                     // repacked conv weights, 147456

    float* AB    = wsf + 393216;
    float* cur   = AB;                                   // f32 [PIX][CC]
    u16*  cur16  = (u16*)(AB + 1048576);
    u16*  xg16   = (u16*)(AB + 1572864);                 // gn-out / attn-out / ln-out / conv-out
    u16*  qkv16  = (u16*)(AB + 2097152);                 // [PIX][384]
    float* abuf  = AB + 2097152;                         // aliases qkv16 (dead)
    u16*  hbuf16 = (u16*)(AB + 3670016);                 // [PIX][512]
    float* ybuf  = AB + 3670016;                         // tail (hbuf dead)
    u16*  y1     = (u16*)(AB + 3670016 + 1048576);       // tail c1-out
    // footprint ≈ (393216 + 5767168)*4B ≈ 24.6 MB

    detect_k<<<1, 256, 0, stream>>>((const u16*)d_in[0], flagp);

    PtrTab tab;
    for(int i = 0; i < 23; i++){ tab.p[i] = d_in[i+1]; tab.off[i] = woff[i]; }
    tab.off[23] = woff[23];
    cvt_all_k<<<(WTOT + 255)/256, 256, 0, stream>>>(tab, Wb, flagp, WTOT);
    repack_conv_k<<<(CC*CC*9 + 255)/256, 256, 0, stream>>>(Wb + woff[13], Wt);

    const u16 *gng = Wb+woff[0], *gnb = Wb+woff[1], *qkvw = Wb+woff[2], *qkvb = Wb+woff[3],
              *projw = Wb+woff[4], *projb = Wb+woff[5], *rpbw = Wb+woff[6], *lng = Wb+woff[7],
              *lnb = Wb+woff[8], *f1w = Wb+woff[9], *f1b = Wb+woff[10], *f2w = Wb+woff[11],
              *f2b = Wb+woff[12], *bcb = Wb+woff[14], *c1w = Wb+woff[15],
              *c1b = Wb+woff[16], *c2w = Wb+woff[17], *c2b = Wb+woff[18], *ca1w = Wb+woff[19],
              *ca1b = Wb+woff[20], *ca2w = Wb+woff[21], *ca2b = Wb+woff[22];

    const int ELEMS = NN*HH*WW*CC;

    nchw2nhwc_k<<<ELEMS/256, 256, 0, stream>>>(d_in[0], cur, flagp);

    for(int l = 0; l < 2; l++){
        gn_r1_k<<<dim3(NN,64), 256, 0, stream>>>(cur, gnpart);
        gn_r2_k<<<NN, 64, 0, stream>>>(gnpart, stats);
        gn_apply_k<<<ELEMS/256, 256, 0, stream>>>(cur, stats, gng + l*CC, gnb + l*CC, xg16);

        mgemm_k<EPI_NONE,OUT_BF16><<<dim3(3, PIX/128), 256, 0, stream>>>(
            xg16, qkvw + (size_t)l*3*CC*CC, qkvb + l*3*CC, nullptr, nullptr, qkv16, PIX, 3*CC, CC);

        att_fused_k<<<PIX, 256, 0, stream>>>(qkv16, rpbw + l*NHD*(2*KSZ-1)*(2*KSZ-1), xg16);

        mgemm_k<EPI_RES,OUT_F32><<<dim3(1, PIX/128), 256, 0, stream>>>(
            xg16, projw + (size_t)l*CC*CC, projb + l*CC, cur, abuf, nullptr, PIX, CC, CC);

        ln_k<<<PIX/4, 256, 0, stream>>>(abuf, lng + l*CC, lnb + l*CC, xg16);

        mgemm_k<EPI_GELU,OUT_BF16><<<dim3(4, PIX/128), 256, 0, stream>>>(
            xg16, f1w + (size_t)l*HID*CC, f1b + l*HID, nullptr, nullptr, hbuf16, PIX, HID, CC);

        mgemm_k<EPI_RES,OUT_BOTH><<<dim3(1, PIX/128), 256, 0, stream>>>(
            hbuf16, f2w + (size_t)l*CC*HID, f2b + l*CC, abuf, cur, cur16, PIX, CC, HID);
    }

    mconv_k<<<dim3(1, PIX/128), 256, 0, stream>>>(cur16, Wt, bcb, xg16);

    mgemm_k<EPI_RELU,OUT_BF16><<<dim3(1, PIX/128), 256, 0, stream>>>(
        xg16, c1w, c1b, nullptr, nullptr, y1, PIX, C4, CC);
    mgemm_k<EPI_NONE,OUT_F32><<<dim3(1, PIX/128), 256, 0, stream>>>(
        y1, c2w, c2b, nullptr, ybuf, nullptr, PIX, CC, C4);

    pool1_k<<<dim3(NN,32), CC, 0, stream>>>(ybuf, popart);
    pool2_k<<<NN, CC, 0, stream>>>(popart, poolb);
    ca_k<<<NN, CC, 0, stream>>>(poolb, ca1w, ca1b, ca2w, ca2b, sbuf);
    final_k<<<ELEMS/256, 256, 0, stream>>>(ybuf, sbuf, d_in[0], d_out, flagp);
}